// Round 21
// baseline (1275.413 us; speedup 1.0000x reference)
//
#include <hip/hip_runtime.h>

#define T_STEPS 2048
#define TOTAL   2064   // T_STEPS + 16 (deepest lag: TT), multiple of 8

typedef float f2 __attribute__((ext_vector_type(2)));
typedef _Float16 h2 __attribute__((ext_vector_type(2)));

__device__ __forceinline__ float fast_rcp(float x) { return __builtin_amdgcn_rcpf(x); }
__device__ __forceinline__ float sig_f(float x) { return fast_rcp(1.0f + __expf(-x)); }
__device__ __forceinline__ float tanh_f(float x) {
    float e = __expf(-2.0f * x);
    return fmaf(2.0f, fast_rcp(1.0f + e), -1.0f);
}
__device__ __forceinline__ float gate_act(float x, float zm, float sm, float sa) {
    float e = __expf(-x * zm);
    return fmaf(fast_rcp(1.0f + e), sm, sa);
}

#if __has_builtin(__builtin_amdgcn_fdot2)
#define FDOT2(a, b, c) __builtin_amdgcn_fdot2((a), (b), (c), false)
#else
__device__ __forceinline__ float FDOT2(h2 a, h2 b, float c) {
    return fmaf((float)a.x, (float)b.x, fmaf((float)a.y, (float)b.y, c));
}
#endif

// Drain ONLY lgkmcnt (LDS) before barrier — never vmcnt (R7 win).
#define LDS_BARRIER() asm volatile("s_waitcnt lgkmcnt(0)\n\ts_barrier" ::: "memory")

#define DPP_BCAST0 0x00
#define DPP_BCAST1 0x55
#define DPP_BCAST2 0xAA
#define DPP_BCAST3 0xFF
#define DPP_PAIR   0xF5
#define DPP_ROR4   0x124
#define DPP_ROR8   0x128
template<int CTRL>
__device__ __forceinline__ float dppf(float x) {
    int r = __builtin_amdgcn_update_dpp(0, __builtin_bit_cast(int, x), CTRL, 0xF, 0xF, true);
    return __builtin_bit_cast(float, r);
}

__device__ __forceinline__ h2 pk16(float a, float b) {
    return __builtin_bit_cast(h2, __builtin_amdgcn_cvt_pkrtz(a, b));
}

__device__ __forceinline__ void unpackh(h2 (&in)[24], const h2* __restrict__ row) {
    const float4* q = (const float4*)row;
#pragma unroll
    for (int k = 0; k < 6; ++k) {
        float4 v = q[k];
        in[4 * k + 0] = __builtin_bit_cast(h2, v.x);
        in[4 * k + 1] = __builtin_bit_cast(h2, v.y);
        in[4 * k + 2] = __builtin_bit_cast(h2, v.z);
        in[4 * k + 3] = __builtin_bit_cast(h2, v.w);
    }
}
__device__ __forceinline__ void unpackx(h2 (&in)[28], const h2* __restrict__ row) {
    const float4* q = (const float4*)row;
#pragma unroll
    for (int k = 0; k < 7; ++k) {
        float4 v = q[k];
        in[4 * k + 0] = __builtin_bit_cast(h2, v.x);
        in[4 * k + 1] = __builtin_bit_cast(h2, v.y);
        in[4 * k + 2] = __builtin_bit_cast(h2, v.z);
        in[4 * k + 3] = __builtin_bit_cast(h2, v.w);
    }
}

__device__ __forceinline__ void loadw47h(h2 (&w)[24], const float* __restrict__ src) {
#pragma unroll
    for (int u = 0; u < 23; ++u)
        w[u] = h2{(_Float16)src[2 * u], (_Float16)src[2 * u + 1]};
    w[23] = h2{(_Float16)src[46], (_Float16)0.0f};
}
__device__ __forceinline__ void loadw49h(h2 (&w)[25], const float* __restrict__ src) {
#pragma unroll
    for (int u = 0; u < 24; ++u)
        w[u] = h2{(_Float16)src[2 * u], (_Float16)src[2 * u + 1]};
    w[24] = h2{(_Float16)src[48], (_Float16)0.0f};
}

__device__ __forceinline__ void loadx4c(float (&dst)[4], const float* __restrict__ x_r,
                                        const float* __restrict__ x_t,
                                        size_t xrb, size_t xtb, int k) {
#pragma unroll
    for (int m = 0; m < 4; ++m) {
        int v = 4 * k + m;
        dst[m] = (v < 47) ? x_r[xrb + v] : ((v < 49) ? x_t[xtb + (v - 47)] : 0.0f);
    }
}

// 3 waves: W0 = layer-0 (lag 0), W1 = layer-1 (lag 8), W2 = t-RNN (lag 16) + x staging.
// R21: per 8-step group, W0/W1 split into PHASE A (x-side dots for all 8 steps ->
// xacc[8][4]; inputs all available at group start: xring written a group ago, W1's
// h0 inputs written by W0 last group, slots disjoint mod 16 from this group's writes)
// and PHASE B (recurrent chain only: h-read -> 24-deep h-dot -> cell -> h-write).
// Removes ~45% of the in-chain issue; phase A fills phase B's stall slots.
__global__ __launch_bounds__(192) void adrnn_fused(
    const float* __restrict__ x_r, const float* __restrict__ x_t,
    const float* __restrict__ rWih0, const float* __restrict__ rWhh0,
    const float* __restrict__ rbih0, const float* __restrict__ rbhh0,
    const float* __restrict__ rWih1, const float* __restrict__ rWhh1,
    const float* __restrict__ rbih1, const float* __restrict__ rbhh1,
    const float* __restrict__ tWih0, const float* __restrict__ tWhh0,
    const float* __restrict__ tbih0, const float* __restrict__ tbhh0,
    const float* __restrict__ tWih1, const float* __restrict__ tWhh1,
    const float* __restrict__ tbih1, const float* __restrict__ tbhh1,
    float* __restrict__ r_out, float* __restrict__ t_out)
{
    __shared__ __align__(16) h2 xring[32][28];
    __shared__ __align__(16) h2 h0f16[16][24];
    __shared__ __align__(16) h2 h1f16[16][24];

    const int tid = threadIdx.x;
    const int wid = tid >> 6;
    const int l   = tid & 63;
    const int j   = l;
    const int b = blockIdx.x;
    const size_t xr_base = (size_t)b * T_STEPS * 47;
    const size_t xt_base = (size_t)b * T_STEPS * 2;

    for (int k = tid; k < 16 * 24; k += 192) {
        h0f16[k / 24][k % 24] = h2{(_Float16)0.0f, (_Float16)0.0f};
        h1f16[k / 24][k % 24] = h2{(_Float16)0.0f, (_Float16)0.0f};
    }

    if (wid == 0) {
        // ===== W0: layer-0 =====
        h2 wx[4][25]; h2 wh[4][24]; float bias[4] = {0, 0, 0, 0};
#pragma unroll
        for (int g = 0; g < 4; ++g) {
#pragma unroll
            for (int u = 0; u < 25; ++u) wx[g][u] = h2{(_Float16)0.0f, (_Float16)0.0f};
#pragma unroll
            for (int u = 0; u < 24; ++u) wh[g][u] = h2{(_Float16)0.0f, (_Float16)0.0f};
        }
        if (j < 47) {
#pragma unroll
            for (int g = 0; g < 4; ++g) {
                const int row = g * 47 + j;
                loadw49h(wx[g], &rWih0[row * 49]);
                loadw47h(wh[g], &rWhh0[row * 47]);
                bias[g] = rbih0[row] + rbhh0[row];
            }
        }
        float c0 = 0.f;
        __syncthreads();
        for (int g0 = 0; g0 < TOTAL; g0 += 8) {
            __builtin_amdgcn_s_setprio(1);
            float xacc[8][4];
            // PHASE A: x-side dots (off the recurrent chain; all inputs group-start-ready)
#pragma unroll
            for (int k8 = 0; k8 < 8; ++k8) {
                const int i = g0 + k8;
                float a0 = bias[0], a1 = bias[1], a2 = bias[2], a3 = bias[3];
                if (i < T_STEPS && j < 47) {
                    h2 xin[28];
                    unpackx(xin, &xring[i & 31][0]);
#pragma unroll
                    for (int u = 0; u < 25; ++u) {
                        a0 = FDOT2(wx[0][u], xin[u], a0);
                        a1 = FDOT2(wx[1][u], xin[u], a1);
                        a2 = FDOT2(wx[2][u], xin[u], a2);
                        a3 = FDOT2(wx[3][u], xin[u], a3);
                    }
                }
                xacc[k8][0] = a0; xacc[k8][1] = a1; xacc[k8][2] = a2; xacc[k8][3] = a3;
            }
            // PHASE B: recurrent chain only
#pragma unroll
            for (int k8 = 0; k8 < 8; ++k8) {
                const int i = g0 + k8;
                float hv = 0.0f;
                if (i < T_STEPS && j < 47) {
                    h2 hin[24];
                    unpackh(hin, &h0f16[(i - 1) & 15][0]);
                    float a0 = xacc[k8][0], a1 = xacc[k8][1], a2 = xacc[k8][2], a3 = xacc[k8][3];
#pragma unroll
                    for (int u = 0; u < 24; ++u) {
                        a0 = FDOT2(wh[0][u], hin[u], a0);
                        a1 = FDOT2(wh[1][u], hin[u], a1);
                        a2 = FDOT2(wh[2][u], hin[u], a2);
                        a3 = FDOT2(wh[3][u], hin[u], a3);
                    }
                    float iv = sig_f(a0), fv = sig_f(a1);
                    float gv = tanh_f(a2), ov = sig_f(a3);
                    c0 = fmaf(fv, c0, iv * gv);
                    hv = ov * tanh_f(c0);
                }
                float hn = dppf<DPP_PAIR>(hv);
                if (i < T_STEPS && j < 47 && !(j & 1)) h0f16[i & 15][j >> 1] = pk16(hv, hn);
            }
            __builtin_amdgcn_s_setprio(0);
            LDS_BARRIER();
        }
    } else if (wid == 1) {
        // ===== W1: layer-1 (lag 8) =====
        h2 wx[4][24]; h2 wh[4][24]; float bias[4] = {0, 0, 0, 0};
#pragma unroll
        for (int g = 0; g < 4; ++g) {
#pragma unroll
            for (int u = 0; u < 24; ++u) {
                wx[g][u] = h2{(_Float16)0.0f, (_Float16)0.0f};
                wh[g][u] = h2{(_Float16)0.0f, (_Float16)0.0f};
            }
        }
        if (j < 47) {
#pragma unroll
            for (int g = 0; g < 4; ++g) {
                const int row = g * 47 + j;
                loadw47h(wx[g], &rWih1[row * 47]);
                loadw47h(wh[g], &rWhh1[row * 47]);
                bias[g] = rbih1[row] + rbhh1[row];
            }
        }
        float c1 = 0.f;
        __syncthreads();
        for (int g0 = 0; g0 < TOTAL; g0 += 8) {
            __builtin_amdgcn_s_setprio(1);
            float xacc[8][4];
            // PHASE A: h0-side dots (h0(s), s in [g0-8, g0), all written last group;
            // ring slots disjoint mod 16 from W0's current-group writes)
#pragma unroll
            for (int k8 = 0; k8 < 8; ++k8) {
                const int s = g0 + k8 - 8;
                float a0 = bias[0], a1 = bias[1], a2 = bias[2], a3 = bias[3];
                if (s >= 0 && s < T_STEPS && j < 47) {
                    h2 xin[24];
                    unpackh(xin, &h0f16[s & 15][0]);
#pragma unroll
                    for (int u = 0; u < 24; ++u) {
                        a0 = FDOT2(wx[0][u], xin[u], a0);
                        a1 = FDOT2(wx[1][u], xin[u], a1);
                        a2 = FDOT2(wx[2][u], xin[u], a2);
                        a3 = FDOT2(wx[3][u], xin[u], a3);
                    }
                }
                xacc[k8][0] = a0; xacc[k8][1] = a1; xacc[k8][2] = a2; xacc[k8][3] = a3;
            }
            // PHASE B: recurrent chain only
#pragma unroll
            for (int k8 = 0; k8 < 8; ++k8) {
                const int s = g0 + k8 - 8;
                float hv = 0.0f;
                if (s >= 0 && s < T_STEPS && j < 47) {
                    h2 hin[24];
                    unpackh(hin, &h1f16[(s - 1) & 15][0]);
                    float a0 = xacc[k8][0], a1 = xacc[k8][1], a2 = xacc[k8][2], a3 = xacc[k8][3];
#pragma unroll
                    for (int u = 0; u < 24; ++u) {
                        a0 = FDOT2(wh[0][u], hin[u], a0);
                        a1 = FDOT2(wh[1][u], hin[u], a1);
                        a2 = FDOT2(wh[2][u], hin[u], a2);
                        a3 = FDOT2(wh[3][u], hin[u], a3);
                    }
                    float iv = sig_f(a0), fv = sig_f(a1);
                    float gv = tanh_f(a2), ov = sig_f(a3);
                    c1 = fmaf(fv, c1, iv * gv);
                    hv = ov * tanh_f(c1);
                    r_out[((size_t)b * T_STEPS + s) * 47 + j] = hv;
                }
                float hn = dppf<DPP_PAIR>(hv);
                if (s >= 0 && s < T_STEPS && j < 47 && !(j & 1)) h1f16[s & 15][j >> 1] = pk16(hv, hn);
            }
            __builtin_amdgcn_s_setprio(0);
            LDS_BARRIER();
        }
    } else {
        // ===== W2: t-RNN (lag 16) + x staging (8 ahead, f16) =====
        const int tu  = (l >> 2) & 1;
        const int tg  = l & 3;
        const int thf = (l >> 3) & 1;
        const int R0 = tg * 2 + tu;
        h2 wt[24]; float wx48;
        if (thf == 0) {
            wx48 = 0.f;
#pragma unroll
            for (int u = 0; u < 24; ++u)
                wt[u] = h2{(_Float16)tWih0[R0 * 96 + 2 * u], (_Float16)tWih0[R0 * 96 + 2 * u + 1]};
        } else {
            wx48 = tWih0[R0 * 96 + 48];
#pragma unroll
            for (int u = 0; u < 23; ++u)
                wt[u] = h2{(_Float16)tWih0[R0 * 96 + 49 + 2 * u], (_Float16)tWih0[R0 * 96 + 49 + 2 * u + 1]};
            wt[23] = h2{(_Float16)tWih0[R0 * 96 + 95], (_Float16)0.0f};
        }
        const float bT0 = tbih0[R0] + tbhh0[R0];
        const float wh00 = tWhh0[R0 * 2 + 0], wh01 = tWhh0[R0 * 2 + 1];
        const float wi10 = tWih1[R0 * 2 + 0], wi11 = tWih1[R0 * 2 + 1];
        const float wh10 = tWhh1[R0 * 2 + 0], wh11 = tWhh1[R0 * 2 + 1];
        const float bT1 = tbih1[R0] + tbhh1[R0];
        const bool isg = (tg == 2);
        const float zm = isg ? 2.f : 1.f, sm = isg ? 2.f : 1.f, sa = isg ? -1.f : 0.f;
        float ht00 = 0.f, ht01 = 0.f, ct0u = 0.f;
        float ht10 = 0.f, ht11 = 0.f, ct1u = 0.f;

        float xa[4] = {0,0,0,0}, xb[4] = {0,0,0,0}, xc[4] = {0,0,0,0};
        if (l < 13) {
            for (int t = 0; t < 8; ++t) {
                float xv[4];
                loadx4c(xv, x_r, x_t, xr_base + (size_t)t * 47, xt_base + (size_t)t * 2, l);
                xring[t][2 * l]     = pk16(xv[0], xv[1]);
                xring[t][2 * l + 1] = pk16(xv[2], xv[3]);
            }
            loadx4c(xa, x_r, x_t, xr_base + (size_t)8 * 47,  xt_base + (size_t)8 * 2,  l);
            loadx4c(xb, x_r, x_t, xr_base + (size_t)9 * 47,  xt_base + (size_t)9 * 2,  l);
            loadx4c(xc, x_r, x_t, xr_base + (size_t)10 * 47, xt_base + (size_t)10 * 2, l);
        }
        __syncthreads();

        for (int g0 = 0; g0 < TOTAL; g0 += 8) {
#pragma unroll
            for (int k8 = 0; k8 < 8; ++k8) {
                const int i = g0 + k8;
                if (l < 13) {
                    const int tw = i + 8;
                    if (tw < T_STEPS) {
                        xring[tw & 31][2 * l]     = pk16(xa[0], xa[1]);
                        xring[tw & 31][2 * l + 1] = pk16(xa[2], xa[3]);
                    }
#pragma unroll
                    for (int m = 0; m < 4; ++m) { xa[m] = xb[m]; xb[m] = xc[m]; }
                    int tl = i + 11;
                    if (tl > T_STEPS - 1) tl = T_STEPS - 1;
                    loadx4c(xc, x_r, x_t, xr_base + (size_t)tl * 47, xt_base + (size_t)tl * 2, l);
                }
                const int s = i - 16;
                if (s >= 0 && s < T_STEPS) {
                    const h2* src = (thf == 0) ? &xring[s & 31][0] : &h1f16[s & 15][0];
                    h2 tin[24];
                    unpackh(tin, src);
                    float x48v = (float)xring[s & 31][24].x;
                    float acc = 0.f;
#pragma unroll
                    for (int u = 0; u < 24; ++u) acc = FDOT2(wt[u], tin[u], acc);
                    float part = (thf == 1) ? fmaf(wx48, x48v, acc) : acc;
                    float pre0 = part + dppf<DPP_ROR8>(part);
                    pre0 += bT0 + wh00 * ht00 + wh01 * ht01;
                    float a0 = gate_act(pre0, zm, sm, sa);
                    float i0 = dppf<DPP_BCAST0>(a0);
                    float f0 = dppf<DPP_BCAST1>(a0);
                    float g0v = dppf<DPP_BCAST2>(a0);
                    float o0 = dppf<DPP_BCAST3>(a0);
                    ct0u = fmaf(f0, ct0u, i0 * g0v);
                    float htu = o0 * tanh_f(ct0u);
                    float hto = dppf<DPP_ROR4>(htu);
                    ht00 = (tu == 0) ? htu : hto;
                    ht01 = (tu == 0) ? hto : htu;
                    float pre1 = bT1 + wi10 * ht00 + wi11 * ht01 + wh10 * ht10 + wh11 * ht11;
                    float a1 = gate_act(pre1, zm, sm, sa);
                    float ji = dppf<DPP_BCAST0>(a1);
                    float jf = dppf<DPP_BCAST1>(a1);
                    float jg = dppf<DPP_BCAST2>(a1);
                    float jo = dppf<DPP_BCAST3>(a1);
                    ct1u = fmaf(jf, ct1u, ji * jg);
                    float h1u = jo * tanh_f(ct1u);
                    float h1o = dppf<DPP_ROR4>(h1u);
                    ht10 = (tu == 0) ? h1u : h1o;
                    ht11 = (tu == 0) ? h1o : h1u;
                    if (l == 0) {
                        float2 tv = {ht10, ht11};
                        *reinterpret_cast<float2*>(&t_out[((size_t)b * T_STEPS + s) * 2]) = tv;
                    }
                }
            }
            LDS_BARRIER();
        }
    }
}

extern "C" void kernel_launch(void* const* d_in, const int* in_sizes, int n_in,
                              void* d_out, int out_size, void* d_ws, size_t ws_size,
                              hipStream_t stream) {
    const float* x_r   = (const float*)d_in[0];
    const float* x_t   = (const float*)d_in[1];
    const float* rWih0 = (const float*)d_in[2];
    const float* rWhh0 = (const float*)d_in[3];
    const float* rbih0 = (const float*)d_in[4];
    const float* rbhh0 = (const float*)d_in[5];
    const float* rWih1 = (const float*)d_in[6];
    const float* rWhh1 = (const float*)d_in[7];
    const float* rbih1 = (const float*)d_in[8];
    const float* rbhh1 = (const float*)d_in[9];
    const float* tWih0 = (const float*)d_in[10];
    const float* tWhh0 = (const float*)d_in[11];
    const float* tbih0 = (const float*)d_in[12];
    const float* tbhh0 = (const float*)d_in[13];
    const float* tWih1 = (const float*)d_in[14];
    const float* tWhh1 = (const float*)d_in[15];
    const float* tbih1 = (const float*)d_in[16];
    const float* tbhh1 = (const float*)d_in[17];

    float* r_out = (float*)d_out;
    float* t_out = r_out + (size_t)256 * T_STEPS * 47;

    hipLaunchKernelGGL(adrnn_fused, dim3(256), dim3(192), 0, stream,
                       x_r, x_t, rWih0, rWhh0, rbih0, rbhh0, rWih1, rWhh1, rbih1, rbhh1,
                       tWih0, tWhh0, tbih0, tbhh0, tWih1, tWhh1, tbih1, tbhh1,
                       r_out, t_out);
}

// Round 22
// 1263.612 us; speedup vs baseline: 1.0093x; 1.0093x over previous
//
#include <hip/hip_runtime.h>

#define T_STEPS 2048
#define TOTAL   2064   // T_STEPS + 16 (deepest lag: TT), multiple of 8

typedef float f2 __attribute__((ext_vector_type(2)));
typedef _Float16 h2 __attribute__((ext_vector_type(2)));

__device__ __forceinline__ float fast_rcp(float x) { return __builtin_amdgcn_rcpf(x); }
__device__ __forceinline__ float sig_f(float x) { return fast_rcp(1.0f + __expf(-x)); }
__device__ __forceinline__ float tanh_f(float x) {
    float e = __expf(-2.0f * x);
    return fmaf(2.0f, fast_rcp(1.0f + e), -1.0f);
}
__device__ __forceinline__ float gate_act(float x, float zm, float sm, float sa) {
    float e = __expf(-x * zm);
    return fmaf(fast_rcp(1.0f + e), sm, sa);
}

#if __has_builtin(__builtin_amdgcn_fdot2)
#define FDOT2(a, b, c) __builtin_amdgcn_fdot2((a), (b), (c), false)
#else
__device__ __forceinline__ float FDOT2(h2 a, h2 b, float c) {
    return fmaf((float)a.x, (float)b.x, fmaf((float)a.y, (float)b.y, c));
}
#endif

// Drain ONLY lgkmcnt (LDS) before barrier — never vmcnt (R7 win).
#define LDS_BARRIER() asm volatile("s_waitcnt lgkmcnt(0)\n\ts_barrier" ::: "memory")

#define DPP_BCAST0 0x00
#define DPP_BCAST1 0x55
#define DPP_BCAST2 0xAA
#define DPP_BCAST3 0xFF
#define DPP_PAIR   0xF5
#define DPP_ROR4   0x124
#define DPP_ROR8   0x128
template<int CTRL>
__device__ __forceinline__ float dppf(float x) {
    int r = __builtin_amdgcn_update_dpp(0, __builtin_bit_cast(int, x), CTRL, 0xF, 0xF, true);
    return __builtin_bit_cast(float, r);
}

__device__ __forceinline__ h2 pk16(float a, float b) {
    return __builtin_bit_cast(h2, __builtin_amdgcn_cvt_pkrtz(a, b));
}

__device__ __forceinline__ void unpackh(h2 (&in)[24], const h2* __restrict__ row) {
    const float4* q = (const float4*)row;
#pragma unroll
    for (int k = 0; k < 6; ++k) {
        float4 v = q[k];
        in[4 * k + 0] = __builtin_bit_cast(h2, v.x);
        in[4 * k + 1] = __builtin_bit_cast(h2, v.y);
        in[4 * k + 2] = __builtin_bit_cast(h2, v.z);
        in[4 * k + 3] = __builtin_bit_cast(h2, v.w);
    }
}
__device__ __forceinline__ void unpackx(h2 (&in)[28], const h2* __restrict__ row) {
    const float4* q = (const float4*)row;
#pragma unroll
    for (int k = 0; k < 7; ++k) {
        float4 v = q[k];
        in[4 * k + 0] = __builtin_bit_cast(h2, v.x);
        in[4 * k + 1] = __builtin_bit_cast(h2, v.y);
        in[4 * k + 2] = __builtin_bit_cast(h2, v.z);
        in[4 * k + 3] = __builtin_bit_cast(h2, v.w);
    }
}

__device__ __forceinline__ void loadw47h(h2 (&w)[24], const float* __restrict__ src) {
#pragma unroll
    for (int u = 0; u < 23; ++u)
        w[u] = h2{(_Float16)src[2 * u], (_Float16)src[2 * u + 1]};
    w[23] = h2{(_Float16)src[46], (_Float16)0.0f};
}
__device__ __forceinline__ void loadw49h(h2 (&w)[25], const float* __restrict__ src) {
#pragma unroll
    for (int u = 0; u < 24; ++u)
        w[u] = h2{(_Float16)src[2 * u], (_Float16)src[2 * u + 1]};
    w[24] = h2{(_Float16)src[48], (_Float16)0.0f};
}

__device__ __forceinline__ void loadx4c(float (&dst)[4], const float* __restrict__ x_r,
                                        const float* __restrict__ x_t,
                                        size_t xrb, size_t xtb, int k) {
#pragma unroll
    for (int m = 0; m < 4; ++m) {
        int v = 4 * k + m;
        dst[m] = (v < 47) ? x_r[xrb + v] : ((v < 49) ? x_t[xtb + (v - 47)] : 0.0f);
    }
}

// 3 waves: W0 = layer-0 (lag 0), W1 = layer-1 (lag 8), W2 = t-RNN (lag 16) + x staging.
// R22: the same-wave h recurrence no longer round-trips through LDS. After the cell,
// even lanes hold pk16(h[j],h[j+1]); 24 v_readlane ops gather the packed h-vector into
// uniform (SGPR) h2 values consumed directly by the next step's FDOT2s. The LDS h-write
// remains only for CROSS-wave consumers (fire-and-forget, off the critical chain).
__global__ __launch_bounds__(192) void adrnn_fused(
    const float* __restrict__ x_r, const float* __restrict__ x_t,
    const float* __restrict__ rWih0, const float* __restrict__ rWhh0,
    const float* __restrict__ rbih0, const float* __restrict__ rbhh0,
    const float* __restrict__ rWih1, const float* __restrict__ rWhh1,
    const float* __restrict__ rbih1, const float* __restrict__ rbhh1,
    const float* __restrict__ tWih0, const float* __restrict__ tWhh0,
    const float* __restrict__ tbih0, const float* __restrict__ tbhh0,
    const float* __restrict__ tWih1, const float* __restrict__ tWhh1,
    const float* __restrict__ tbih1, const float* __restrict__ tbhh1,
    float* __restrict__ r_out, float* __restrict__ t_out)
{
    __shared__ __align__(16) h2 xring[32][28];
    __shared__ __align__(16) h2 h0f16[16][24];
    __shared__ __align__(16) h2 h1f16[16][24];

    const int tid = threadIdx.x;
    const int wid = tid >> 6;
    const int l   = tid & 63;
    const int j   = l;
    const int b = blockIdx.x;
    const size_t xr_base = (size_t)b * T_STEPS * 47;
    const size_t xt_base = (size_t)b * T_STEPS * 2;

    for (int k = tid; k < 16 * 24; k += 192) {
        h0f16[k / 24][k % 24] = h2{(_Float16)0.0f, (_Float16)0.0f};
        h1f16[k / 24][k % 24] = h2{(_Float16)0.0f, (_Float16)0.0f};
    }

    if (wid == 0) {
        // ===== W0: layer-0 =====
        h2 wx[4][25]; h2 wh[4][24]; float bias[4] = {0, 0, 0, 0};
#pragma unroll
        for (int g = 0; g < 4; ++g) {
#pragma unroll
            for (int u = 0; u < 25; ++u) wx[g][u] = h2{(_Float16)0.0f, (_Float16)0.0f};
#pragma unroll
            for (int u = 0; u < 24; ++u) wh[g][u] = h2{(_Float16)0.0f, (_Float16)0.0f};
        }
        if (j < 47) {
#pragma unroll
            for (int g = 0; g < 4; ++g) {
                const int row = g * 47 + j;
                loadw49h(wx[g], &rWih0[row * 49]);
                loadw47h(wh[g], &rWhh0[row * 47]);
                bias[g] = rbih0[row] + rbhh0[row];
            }
        }
        float c0 = 0.f;
        int hr[24];                      // packed h0(i-1): uniform (SGPR) h2 values
#pragma unroll
        for (int u = 0; u < 24; ++u) hr[u] = 0;
        __syncthreads();
        for (int g0 = 0; g0 < TOTAL; g0 += 8) {
            __builtin_amdgcn_s_setprio(1);
            float xacc[8][4];
            // PHASE A: x-side dots (off-chain)
#pragma unroll
            for (int k8 = 0; k8 < 8; ++k8) {
                const int i = g0 + k8;
                float a0 = bias[0], a1 = bias[1], a2 = bias[2], a3 = bias[3];
                if (i < T_STEPS && j < 47) {
                    h2 xin[28];
                    unpackx(xin, &xring[i & 31][0]);
#pragma unroll
                    for (int u = 0; u < 25; ++u) {
                        a0 = FDOT2(wx[0][u], xin[u], a0);
                        a1 = FDOT2(wx[1][u], xin[u], a1);
                        a2 = FDOT2(wx[2][u], xin[u], a2);
                        a3 = FDOT2(wx[3][u], xin[u], a3);
                    }
                }
                xacc[k8][0] = a0; xacc[k8][1] = a1; xacc[k8][2] = a2; xacc[k8][3] = a3;
            }
            // PHASE B: recurrent chain — h from registers (readlane), no LDS round-trip
#pragma unroll
            for (int k8 = 0; k8 < 8; ++k8) {
                const int i = g0 + k8;
                float hv = 0.0f;
                if (i < T_STEPS && j < 47) {
                    float a0 = xacc[k8][0], a1 = xacc[k8][1], a2 = xacc[k8][2], a3 = xacc[k8][3];
#pragma unroll
                    for (int u = 0; u < 24; ++u) {
                        h2 hu = __builtin_bit_cast(h2, hr[u]);
                        a0 = FDOT2(wh[0][u], hu, a0);
                        a1 = FDOT2(wh[1][u], hu, a1);
                        a2 = FDOT2(wh[2][u], hu, a2);
                        a3 = FDOT2(wh[3][u], hu, a3);
                    }
                    float iv = sig_f(a0), fv = sig_f(a1);
                    float gv = tanh_f(a2), ov = sig_f(a3);
                    c0 = fmaf(fv, c0, iv * gv);
                    hv = ov * tanh_f(c0);
                }
                float hn = dppf<DPP_PAIR>(hv);
                h2 pk = pk16(hv, hn);
                if (i < T_STEPS) {
                    const int pki = __builtin_bit_cast(int, pk);
#pragma unroll
                    for (int u = 0; u < 24; ++u)
                        hr[u] = __builtin_amdgcn_readlane(pki, 2 * u);
                    if (j < 47 && !(j & 1)) h0f16[i & 15][j >> 1] = pk;  // cross-wave only
                }
            }
            __builtin_amdgcn_s_setprio(0);
            LDS_BARRIER();
        }
    } else if (wid == 1) {
        // ===== W1: layer-1 (lag 8) =====
        h2 wx[4][24]; h2 wh[4][24]; float bias[4] = {0, 0, 0, 0};
#pragma unroll
        for (int g = 0; g < 4; ++g) {
#pragma unroll
            for (int u = 0; u < 24; ++u) {
                wx[g][u] = h2{(_Float16)0.0f, (_Float16)0.0f};
                wh[g][u] = h2{(_Float16)0.0f, (_Float16)0.0f};
            }
        }
        if (j < 47) {
#pragma unroll
            for (int g = 0; g < 4; ++g) {
                const int row = g * 47 + j;
                loadw47h(wx[g], &rWih1[row * 47]);
                loadw47h(wh[g], &rWhh1[row * 47]);
                bias[g] = rbih1[row] + rbhh1[row];
            }
        }
        float c1 = 0.f;
        int hr[24];                      // packed h1(s-1)
#pragma unroll
        for (int u = 0; u < 24; ++u) hr[u] = 0;
        __syncthreads();
        for (int g0 = 0; g0 < TOTAL; g0 += 8) {
            __builtin_amdgcn_s_setprio(1);
            float xacc[8][4];
            // PHASE A: h0-side dots (cross-wave input, written last group)
#pragma unroll
            for (int k8 = 0; k8 < 8; ++k8) {
                const int s = g0 + k8 - 8;
                float a0 = bias[0], a1 = bias[1], a2 = bias[2], a3 = bias[3];
                if (s >= 0 && s < T_STEPS && j < 47) {
                    h2 xin[24];
                    unpackh(xin, &h0f16[s & 15][0]);
#pragma unroll
                    for (int u = 0; u < 24; ++u) {
                        a0 = FDOT2(wx[0][u], xin[u], a0);
                        a1 = FDOT2(wx[1][u], xin[u], a1);
                        a2 = FDOT2(wx[2][u], xin[u], a2);
                        a3 = FDOT2(wx[3][u], xin[u], a3);
                    }
                }
                xacc[k8][0] = a0; xacc[k8][1] = a1; xacc[k8][2] = a2; xacc[k8][3] = a3;
            }
            // PHASE B: recurrent chain — h from registers
#pragma unroll
            for (int k8 = 0; k8 < 8; ++k8) {
                const int s = g0 + k8 - 8;
                float hv = 0.0f;
                if (s >= 0 && s < T_STEPS && j < 47) {
                    float a0 = xacc[k8][0], a1 = xacc[k8][1], a2 = xacc[k8][2], a3 = xacc[k8][3];
#pragma unroll
                    for (int u = 0; u < 24; ++u) {
                        h2 hu = __builtin_bit_cast(h2, hr[u]);
                        a0 = FDOT2(wh[0][u], hu, a0);
                        a1 = FDOT2(wh[1][u], hu, a1);
                        a2 = FDOT2(wh[2][u], hu, a2);
                        a3 = FDOT2(wh[3][u], hu, a3);
                    }
                    float iv = sig_f(a0), fv = sig_f(a1);
                    float gv = tanh_f(a2), ov = sig_f(a3);
                    c1 = fmaf(fv, c1, iv * gv);
                    hv = ov * tanh_f(c1);
                    r_out[((size_t)b * T_STEPS + s) * 47 + j] = hv;
                }
                float hn = dppf<DPP_PAIR>(hv);
                h2 pk = pk16(hv, hn);
                if (s >= 0 && s < T_STEPS) {
                    const int pki = __builtin_bit_cast(int, pk);
#pragma unroll
                    for (int u = 0; u < 24; ++u)
                        hr[u] = __builtin_amdgcn_readlane(pki, 2 * u);
                    if (j < 47 && !(j & 1)) h1f16[s & 15][j >> 1] = pk;  // cross-wave only
                }
            }
            __builtin_amdgcn_s_setprio(0);
            LDS_BARRIER();
        }
    } else {
        // ===== W2: t-RNN (lag 16) + x staging (8 ahead, f16) =====
        const int tu  = (l >> 2) & 1;
        const int tg  = l & 3;
        const int thf = (l >> 3) & 1;
        const int R0 = tg * 2 + tu;
        h2 wt[24]; float wx48;
        if (thf == 0) {
            wx48 = 0.f;
#pragma unroll
            for (int u = 0; u < 24; ++u)
                wt[u] = h2{(_Float16)tWih0[R0 * 96 + 2 * u], (_Float16)tWih0[R0 * 96 + 2 * u + 1]};
        } else {
            wx48 = tWih0[R0 * 96 + 48];
#pragma unroll
            for (int u = 0; u < 23; ++u)
                wt[u] = h2{(_Float16)tWih0[R0 * 96 + 49 + 2 * u], (_Float16)tWih0[R0 * 96 + 49 + 2 * u + 1]};
            wt[23] = h2{(_Float16)tWih0[R0 * 96 + 95], (_Float16)0.0f};
        }
        const float bT0 = tbih0[R0] + tbhh0[R0];
        const float wh00 = tWhh0[R0 * 2 + 0], wh01 = tWhh0[R0 * 2 + 1];
        const float wi10 = tWih1[R0 * 2 + 0], wi11 = tWih1[R0 * 2 + 1];
        const float wh10 = tWhh1[R0 * 2 + 0], wh11 = tWhh1[R0 * 2 + 1];
        const float bT1 = tbih1[R0] + tbhh1[R0];
        const bool isg = (tg == 2);
        const float zm = isg ? 2.f : 1.f, sm = isg ? 2.f : 1.f, sa = isg ? -1.f : 0.f;
        float ht00 = 0.f, ht01 = 0.f, ct0u = 0.f;
        float ht10 = 0.f, ht11 = 0.f, ct1u = 0.f;

        float xa[4] = {0,0,0,0}, xb[4] = {0,0,0,0}, xc[4] = {0,0,0,0};
        if (l < 13) {
            for (int t = 0; t < 8; ++t) {
                float xv[4];
                loadx4c(xv, x_r, x_t, xr_base + (size_t)t * 47, xt_base + (size_t)t * 2, l);
                xring[t][2 * l]     = pk16(xv[0], xv[1]);
                xring[t][2 * l + 1] = pk16(xv[2], xv[3]);
            }
            loadx4c(xa, x_r, x_t, xr_base + (size_t)8 * 47,  xt_base + (size_t)8 * 2,  l);
            loadx4c(xb, x_r, x_t, xr_base + (size_t)9 * 47,  xt_base + (size_t)9 * 2,  l);
            loadx4c(xc, x_r, x_t, xr_base + (size_t)10 * 47, xt_base + (size_t)10 * 2, l);
        }
        __syncthreads();

        for (int g0 = 0; g0 < TOTAL; g0 += 8) {
#pragma unroll
            for (int k8 = 0; k8 < 8; ++k8) {
                const int i = g0 + k8;
                if (l < 13) {
                    const int tw = i + 8;
                    if (tw < T_STEPS) {
                        xring[tw & 31][2 * l]     = pk16(xa[0], xa[1]);
                        xring[tw & 31][2 * l + 1] = pk16(xa[2], xa[3]);
                    }
#pragma unroll
                    for (int m = 0; m < 4; ++m) { xa[m] = xb[m]; xb[m] = xc[m]; }
                    int tl = i + 11;
                    if (tl > T_STEPS - 1) tl = T_STEPS - 1;
                    loadx4c(xc, x_r, x_t, xr_base + (size_t)tl * 47, xt_base + (size_t)tl * 2, l);
                }
                const int s = i - 16;
                if (s >= 0 && s < T_STEPS) {
                    const h2* src = (thf == 0) ? &xring[s & 31][0] : &h1f16[s & 15][0];
                    h2 tin[24];
                    unpackh(tin, src);
                    float x48v = (float)xring[s & 31][24].x;
                    float acc = 0.f;
#pragma unroll
                    for (int u = 0; u < 24; ++u) acc = FDOT2(wt[u], tin[u], acc);
                    float part = (thf == 1) ? fmaf(wx48, x48v, acc) : acc;
                    float pre0 = part + dppf<DPP_ROR8>(part);
                    pre0 += bT0 + wh00 * ht00 + wh01 * ht01;
                    float a0 = gate_act(pre0, zm, sm, sa);
                    float i0 = dppf<DPP_BCAST0>(a0);
                    float f0 = dppf<DPP_BCAST1>(a0);
                    float g0v = dppf<DPP_BCAST2>(a0);
                    float o0 = dppf<DPP_BCAST3>(a0);
                    ct0u = fmaf(f0, ct0u, i0 * g0v);
                    float htu = o0 * tanh_f(ct0u);
                    float hto = dppf<DPP_ROR4>(htu);
                    ht00 = (tu == 0) ? htu : hto;
                    ht01 = (tu == 0) ? hto : htu;
                    float pre1 = bT1 + wi10 * ht00 + wi11 * ht01 + wh10 * ht10 + wh11 * ht11;
                    float a1 = gate_act(pre1, zm, sm, sa);
                    float ji = dppf<DPP_BCAST0>(a1);
                    float jf = dppf<DPP_BCAST1>(a1);
                    float jg = dppf<DPP_BCAST2>(a1);
                    float jo = dppf<DPP_BCAST3>(a1);
                    ct1u = fmaf(jf, ct1u, ji * jg);
                    float h1u = jo * tanh_f(ct1u);
                    float h1o = dppf<DPP_ROR4>(h1u);
                    ht10 = (tu == 0) ? h1u : h1o;
                    ht11 = (tu == 0) ? h1o : h1u;
                    if (l == 0) {
                        float2 tv = {ht10, ht11};
                        *reinterpret_cast<float2*>(&t_out[((size_t)b * T_STEPS + s) * 2]) = tv;
                    }
                }
            }
            LDS_BARRIER();
        }
    }
}

extern "C" void kernel_launch(void* const* d_in, const int* in_sizes, int n_in,
                              void* d_out, int out_size, void* d_ws, size_t ws_size,
                              hipStream_t stream) {
    const float* x_r   = (const float*)d_in[0];
    const float* x_t   = (const float*)d_in[1];
    const float* rWih0 = (const float*)d_in[2];
    const float* rWhh0 = (const float*)d_in[3];
    const float* rbih0 = (const float*)d_in[4];
    const float* rbhh0 = (const float*)d_in[5];
    const float* rWih1 = (const float*)d_in[6];
    const float* rWhh1 = (const float*)d_in[7];
    const float* rbih1 = (const float*)d_in[8];
    const float* rbhh1 = (const float*)d_in[9];
    const float* tWih0 = (const float*)d_in[10];
    const float* tWhh0 = (const float*)d_in[11];
    const float* tbih0 = (const float*)d_in[12];
    const float* tbhh0 = (const float*)d_in[13];
    const float* tWih1 = (const float*)d_in[14];
    const float* tWhh1 = (const float*)d_in[15];
    const float* tbih1 = (const float*)d_in[16];
    const float* tbhh1 = (const float*)d_in[17];

    float* r_out = (float*)d_out;
    float* t_out = r_out + (size_t)256 * T_STEPS * 47;

    hipLaunchKernelGGL(adrnn_fused, dim3(256), dim3(192), 0, stream,
                       x_r, x_t, rWih0, rWhh0, rbih0, rbhh0, rWih1, rWhh1, rbih1, rbhh1,
                       tWih0, tWhh0, tbih0, tbhh0, tWih1, tWhh1, tbih1, tbhh1,
                       r_out, t_out);
}